// Round 8
// baseline (101.264 us; speedup 1.0000x reference)
//
#include <hip/hip_runtime.h>

// LGA2 fused: out = LGA(LGA(x,f),f), radius=2 (25 taps), fp32.
// x: [N=2, C=64, H=256, W=512], f: [N, 25, H, W], out like x.
//
// R8 vs R7:
//  - 2-channel unroll: 4 lgkm-barriers serve TWO channels (R7: 4 per one).
//    st/sp double-buffered; staggered prefetch (c+2 lands after bar1,
//    c+3 after bar3) so only one f4 prefetch reg is live at a time.
//  - amdgpu_waves_per_eu(4,6): VGPR budget 128 so A-set's 60 filter regs
//    stay fully resident (R7: VGPR=52 < 60 => residual spill at the
//    default 8-waves/SIMD target).
// Structure: 512 thr; set A (tid<256) = taps 0-14, set B = taps 15-24
// (names F0..F9 shared). A writes f4 partials to sp; B combines.
// Tile: temp 16x64, out 12x60, x region 20x68, stride 68 dwords.

typedef float f4 __attribute__((ext_vector_type(4)));
typedef float f2 __attribute__((ext_vector_type(2)));

#define OH 12
#define OW 60
#define STS 68
#define SXN (20 * STS)   // 1360 dwords per x buffer

#define TAPF(F,u0,u1,u2,u3) { a0=fmaf(F.x,u0,a0); a1=fmaf(F.y,u1,a1); \
                              a2=fmaf(F.z,u2,a2); a3=fmaf(F.w,u3,a3); }
#define ROW5(Fa,Fb,Fc,Fd,Fe,P) { const f4 xa=*(const f4*)(P); const f4 xb=*(const f4*)((P)+4); \
  TAPF(Fa,xa.x,xa.y,xa.z,xa.w) TAPF(Fb,xa.y,xa.z,xa.w,xb.x) TAPF(Fc,xa.z,xa.w,xb.x,xb.y) \
  TAPF(Fd,xa.w,xb.x,xb.y,xb.z) TAPF(Fe,xb.x,xb.y,xb.z,xb.w) }

// lgkm-only barrier: LDS ordered, global prefetch loads stay in flight
#define LBAR() { asm volatile("s_waitcnt lgkmcnt(0)" ::: "memory"); \
                 __builtin_amdgcn_s_barrier(); asm volatile("" ::: "memory"); }

__global__ __launch_bounds__(512)
__attribute__((amdgpu_waves_per_eu(4, 6)))
void lga2_fused(const float* __restrict__ x, const float* __restrict__ f,
                float* __restrict__ out, int N, int C, int H, int W, int CPB) {
    const int tid = threadIdx.x;
    const bool isA = (tid < 256);
    const int t = tid & 255;
    const int r = t >> 4;              // temp-region row 0..15
    const int s = t & 15;              // quad-strip 0..15
    const int oh0 = blockIdx.y * OH;
    const int ow0 = blockIdx.x * OW;
    const int CG = C / CPB;
    const int n  = blockIdx.z / CG;
    const int c0 = (blockIdx.z % CG) * CPB;
    const int HW = H * W;

    __shared__ float sx0[SXN], sx1[SXN];
    __shared__ float st0[16 * STS], st1[16 * STS];   // temp (2 ch)
    __shared__ float sp0[16 * STS], sp1[16 * STS];   // A-partial exchange

    if (tid < 128) {                  // zero temp guard cols once (both st)
        int i = tid & 63;
        int zr = i >> 2, q = i & 3;
        float* stz = (tid < 64) ? st0 : st1;
        stz[zr * STS + (q < 2 ? q : q + 64)] = 0.0f;
    }

    // ---- filter registers (named SSA f4 vars) ----
    const int gh_f = oh0 - 2 + r;
    const int gwb  = ow0 - 2 + 4 * s;
    const bool rowok = (gh_f >= 0) && (gh_f < H);
    const bool p0ok = rowok && (gwb >= 0) && (gwb + 1 < W);
    const bool p1ok = rowok && (gwb + 3 < W);
    const float* fb = f + (size_t)(n * 25) * HW + (size_t)(rowok ? gh_f : 0) * W;

#define LDF(T) ({ f2 u_ = p0ok ? *(const f2*)(fb + (size_t)(T) * HW + gwb)     : f2{0.f, 0.f}; \
                  f2 v_ = p1ok ? *(const f2*)(fb + (size_t)(T) * HW + gwb + 2) : f2{0.f, 0.f}; \
                  f4{u_.x, u_.y, v_.x, v_.y}; })
#define PIN(F) asm volatile("" : "+v"(F));

    f4 F0,F1,F2,F3,F4,F5,F6,F7,F8,F9,F10,F11,F12,F13,F14;
    F10 = F11 = F12 = F13 = F14 = f4{0.f,0.f,0.f,0.f};
    if (isA) {
        F0=LDF(0); F1=LDF(1); F2=LDF(2); F3=LDF(3); F4=LDF(4);
        F5=LDF(5); F6=LDF(6); F7=LDF(7); F8=LDF(8); F9=LDF(9);
        F10=LDF(10); F11=LDF(11); F12=LDF(12); F13=LDF(13); F14=LDF(14);
        PIN(F10) PIN(F11) PIN(F12) PIN(F13) PIN(F14)
    } else {
        F0=LDF(15); F1=LDF(16); F2=LDF(17); F3=LDF(18); F4=LDF(19);
        F5=LDF(20); F6=LDF(21); F7=LDF(22); F8=LDF(23); F9=LDF(24);
    }
    PIN(F0) PIN(F1) PIN(F2) PIN(F3) PIN(F4)
    PIN(F5) PIN(F6) PIN(F7) PIN(F8) PIN(F9)

    // ---- staging geometry: 340 quads, one per thread (tid<340), linear ----
    const bool stg = (tid < 340);
    const int row0 = tid / 17, v0 = tid - row0 * 17;
    const int g0h = oh0 - 4 + row0, g0c = ow0 - 4 + 4 * v0;
    const bool ok0 = stg && (g0h >= 0) && (g0h < H) && (g0c >= 0) && (g0c + 3 < W);
    const int off0 = ok0 ? (g0h * W + g0c) : 0;
    const int l0 = 4 * tid;
    const f4 z4 = f4{0.f, 0.f, 0.f, 0.f};
    const float* xc = x + (size_t)(n * C + c0) * HW;

    if (stg) {                         // prologue: stage channels 0,1
        f4 p = ok0 ? *(const f4*)(xc + off0) : z4;
        *(f4*)&sx0[l0] = p;
        f4 q = ok0 ? *(const f4*)(xc + HW + off0) : z4;
        *(f4*)&sx1[l0] = q;
    }
    __syncthreads();

    const bool prow = (r >= 2) && (r <= 13) && (gh_f < H);

    for (int cc = 0; cc < CPB; cc += 2) {
        const bool pf0 = (cc + 2 < CPB);
        // issue prefetch for channel cc+2 (lands after bar1)
        f4 nx0 = z4;
        if (pf0 && ok0) nx0 = *(const f4*)(xc + (size_t)(cc + 2) * HW + off0);

        float pa0=0.f,pa1=0.f,pa2=0.f,pa3=0.f, pb0=0.f,pb1=0.f,pb2=0.f,pb3=0.f;

        // ---- pass 1, both channels ----
        if (isA) {
            { float a0=0.f,a1=0.f,a2=0.f,a3=0.f;
              const float* P0 = sx0 + r * STS + 4 * s;
              ROW5(F0,F1,F2,F3,F4,   P0)
              ROW5(F5,F6,F7,F8,F9,   P0 + STS)
              ROW5(F10,F11,F12,F13,F14, P0 + 2 * STS)
              *(f4*)&sp0[r * STS + 4 * s] = f4{a0, a1, a2, a3}; }
            { float a0=0.f,a1=0.f,a2=0.f,a3=0.f;
              const float* P0 = sx1 + r * STS + 4 * s;
              ROW5(F0,F1,F2,F3,F4,   P0)
              ROW5(F5,F6,F7,F8,F9,   P0 + STS)
              ROW5(F10,F11,F12,F13,F14, P0 + 2 * STS)
              *(f4*)&sp1[r * STS + 4 * s] = f4{a0, a1, a2, a3}; }
        } else {
            { float a0=0.f,a1=0.f,a2=0.f,a3=0.f;
              const float* P3 = sx0 + (r + 3) * STS + 4 * s;
              ROW5(F0,F1,F2,F3,F4,   P3)
              ROW5(F5,F6,F7,F8,F9,   P3 + STS)
              pa0=a0; pa1=a1; pa2=a2; pa3=a3; }
            { float a0=0.f,a1=0.f,a2=0.f,a3=0.f;
              const float* P3 = sx1 + (r + 3) * STS + 4 * s;
              ROW5(F0,F1,F2,F3,F4,   P3)
              ROW5(F5,F6,F7,F8,F9,   P3 + STS)
              pb0=a0; pb1=a1; pb2=a2; pb3=a3; }
        }
        LBAR();   // bar1: sp (p1 A-partials) visible; sx reads complete

        if (!isA) {                    // combine -> temp, both channels
            f4 qa = *(const f4*)&sp0[r * STS + 4 * s];
            *(f2*)&st0[r * STS + 2 + 4 * s] = f2{qa.x + pa0, qa.y + pa1};
            *(f2*)&st0[r * STS + 4 + 4 * s] = f2{qa.z + pa2, qa.w + pa3};
            f4 qb = *(const f4*)&sp1[r * STS + 4 * s];
            *(f2*)&st1[r * STS + 2 + 4 * s] = f2{qb.x + pb0, qb.y + pb1};
            *(f2*)&st1[r * STS + 4 + 4 * s] = f2{qb.z + pb2, qb.w + pb3};
        }
        // land prefetch cc+2 into sx0 (its reads completed before bar1)
        if (pf0 && stg) *(f4*)&sx0[l0] = nx0;
        // issue prefetch for channel cc+3 (lands after bar3)
        const bool pf1 = (cc + 3 < CPB);
        f4 nx1 = z4;
        if (pf1 && ok0) nx1 = *(const f4*)(xc + (size_t)(cc + 3) * HW + off0);
        LBAR();   // bar2: st (temp) visible

        // ---- pass 2, both channels ----
        if (isA) {
            if (prow) {
                { float a0=0.f,a1=0.f,a2=0.f,a3=0.f;
                  const float* Q0 = st0 + (r - 2) * STS + 4 * s;
                  ROW5(F0,F1,F2,F3,F4,   Q0)
                  ROW5(F5,F6,F7,F8,F9,   Q0 + STS)
                  ROW5(F10,F11,F12,F13,F14, Q0 + 2 * STS)
                  *(f4*)&sp0[r * STS + 4 * s] = f4{a0, a1, a2, a3}; }
                { float a0=0.f,a1=0.f,a2=0.f,a3=0.f;
                  const float* Q0 = st1 + (r - 2) * STS + 4 * s;
                  ROW5(F0,F1,F2,F3,F4,   Q0)
                  ROW5(F5,F6,F7,F8,F9,   Q0 + STS)
                  ROW5(F10,F11,F12,F13,F14, Q0 + 2 * STS)
                  *(f4*)&sp1[r * STS + 4 * s] = f4{a0, a1, a2, a3}; }
            }
        } else if (prow) {
            { float a0=0.f,a1=0.f,a2=0.f,a3=0.f;
              const float* Q3 = st0 + (r + 1) * STS + 4 * s;
              ROW5(F0,F1,F2,F3,F4,   Q3)
              ROW5(F5,F6,F7,F8,F9,   Q3 + STS)
              pa0=a0; pa1=a1; pa2=a2; pa3=a3; }
            { float a0=0.f,a1=0.f,a2=0.f,a3=0.f;
              const float* Q3 = st1 + (r + 1) * STS + 4 * s;
              ROW5(F0,F1,F2,F3,F4,   Q3)
              ROW5(F5,F6,F7,F8,F9,   Q3 + STS)
              pb0=a0; pb1=a1; pb2=a2; pb3=a3; }
        }
        LBAR();   // bar3: sp (p2 A-partials) visible

        if (!isA && prow) {            // combine -> global, both channels
            f4 qa = *(const f4*)&sp0[r * STS + 4 * s];
            float* op = out + ((size_t)(n * C + c0 + cc) * H + gh_f) * W + gwb;
            if (s >= 1 && gwb + 1 < W)  *(f2*)op       = f2{qa.x + pa0, qa.y + pa1};
            if (s <= 14 && gwb + 3 < W) *(f2*)(op + 2) = f2{qa.z + pa2, qa.w + pa3};
            f4 qb = *(const f4*)&sp1[r * STS + 4 * s];
            float* oq = op + (size_t)HW;   // next channel, same (h,w)
            if (s >= 1 && gwb + 1 < W)  *(f2*)oq       = f2{qb.x + pb0, qb.y + pb1};
            if (s <= 14 && gwb + 3 < W) *(f2*)(oq + 2) = f2{qb.z + pb2, qb.w + pb3};
        }
        // land prefetch cc+3 into sx1 (its reads completed before bar1)
        if (pf1 && stg) *(f4*)&sx1[l0] = nx1;
        LBAR();   // bar4: next channels' x visible
    }
}

extern "C" void kernel_launch(void* const* d_in, const int* in_sizes, int n_in,
                              void* d_out, int out_size, void* d_ws, size_t ws_size,
                              hipStream_t stream) {
    const float* x = (const float*)d_in[0];
    const float* f = (const float*)d_in[1];
    float* out = (float*)d_out;

    const int N = 2, C = 64, H = 256, W = 512;
    const int CPB = 32;
    const int CG = C / CPB;                    // 2

    dim3 grid((W + OW - 1) / OW,               // 9
              (H + OH - 1) / OH,               // 22
              N * CG);                         // 4  -> 792 blocks of 512 thr
    lga2_fused<<<grid, 512, 0, stream>>>(x, f, out, N, C, H, W, CPB);
}